// Round 10
// baseline (165.637 us; speedup 1.0000x reference)
//
#include <hip/hip_runtime.h>
#include <hip/hip_bf16.h>

#define SS 2048

typedef __attribute__((ext_vector_type(8))) short bf16x8;
typedef __attribute__((ext_vector_type(4))) float f32x4;

__device__ __forceinline__ short f2bf(float f){
    unsigned u = __float_as_uint(f);
    u += 0x7fff + ((u >> 16) & 1);   // RNE; inputs finite
    return (short)(u >> 16);
}

// ---------------------------------------------------------------------------
// K0a: weight prep with coalesced reads + LDS transpose.
// blocks 0..191: WcatT[768][1024]  (q:0.125*group-sum | k | v), bf16, B^T layout
// blocks 192..255: WoT[1024][256] = Wo^T, bf16
__global__ __launch_bounds__(256) void k_prep_w(const float* __restrict__ Wq,
                                                const float* __restrict__ Wk,
                                                const float* __restrict__ Wv,
                                                const float* __restrict__ Wo,
                                                short* __restrict__ WcatT,
                                                short* __restrict__ WoT){
    __shared__ float Ts[64][65];
    const int bx = blockIdx.x;
    const int r  = threadIdx.x >> 2;
    const int cq = (threadIdx.x & 3) * 16;
    if (bx < 192) {
        const int ktile = bx & 15, ntile = bx >> 4;   // k0 in [0,1024), n0 in [0,768)
        const int k0 = ktile * 64, n0 = ntile * 64;
        if (ntile < 4) {   // q: sum 4 group columns + 0.125 scale
            const float* base = Wq + (size_t)(k0 + r) * 1024 + ntile * 256;
            #pragma unroll
            for (int i = 0; i < 16; i += 4) {
                float4 a = *(const float4*)(base + cq + i);
                float4 b = *(const float4*)(base + 64 + cq + i);
                float4 c = *(const float4*)(base + 128 + cq + i);
                float4 d = *(const float4*)(base + 192 + cq + i);
                Ts[r][cq+i]   = 0.125f * (a.x + b.x + c.x + d.x);
                Ts[r][cq+i+1] = 0.125f * (a.y + b.y + c.y + d.y);
                Ts[r][cq+i+2] = 0.125f * (a.z + b.z + c.z + d.z);
                Ts[r][cq+i+3] = 0.125f * (a.w + b.w + c.w + d.w);
            }
        } else {
            const float* W = (ntile < 8) ? Wk : Wv;
            const float* base = W + (size_t)(k0 + r) * 256 + (ntile & 3) * 64;
            #pragma unroll
            for (int i = 0; i < 16; i += 4) {
                float4 a = *(const float4*)(base + cq + i);
                Ts[r][cq+i] = a.x; Ts[r][cq+i+1] = a.y;
                Ts[r][cq+i+2] = a.z; Ts[r][cq+i+3] = a.w;
            }
        }
        __syncthreads();
        short tmp[16];
        #pragma unroll
        for (int i = 0; i < 16; ++i) tmp[i] = f2bf(Ts[cq+i][r]);
        short* dst = WcatT + (size_t)(n0 + r) * 1024 + k0 + cq;
        *(bf16x8*)dst       = *(bf16x8*)&tmp[0];
        *(bf16x8*)(dst + 8) = *(bf16x8*)&tmp[8];
    } else {
        const int b2 = bx - 192;
        const int ktile = b2 & 3, ntile = b2 >> 2;    // k0 in [0,256), n0 in [0,1024)
        const int k0 = ktile * 64, n0 = ntile * 64;
        const float* base = Wo + (size_t)(k0 + r) * 1024 + n0;
        #pragma unroll
        for (int i = 0; i < 16; i += 4) {
            float4 a = *(const float4*)(base + cq + i);
            Ts[r][cq+i] = a.x; Ts[r][cq+i+1] = a.y;
            Ts[r][cq+i+2] = a.z; Ts[r][cq+i+3] = a.w;
        }
        __syncthreads();
        short tmp[16];
        #pragma unroll
        for (int i = 0; i < 16; ++i) tmp[i] = f2bf(Ts[cq+i][r]);
        short* dst = WoT + (size_t)(n0 + r) * 256 + k0 + cq;
        *(bf16x8*)dst       = *(bf16x8*)&tmp[0];
        *(bf16x8*)(dst + 8) = *(bf16x8*)&tmp[8];
    }
}

// K0b: q_in/kv_in fp32 -> bf16 flat (8 MB each, correctly sized). grid (4096, 2)
__global__ __launch_bounds__(256) void k_prep_x(const float* __restrict__ q_in,
                                                const float* __restrict__ kv_in,
                                                short* __restrict__ xq,
                                                short* __restrict__ xkv){
    const float* src = blockIdx.y ? kv_in : q_in;
    short* dst = blockIdx.y ? xkv : xq;
    int i = (blockIdx.x * 256 + threadIdx.x) * 4;
    float4 f = *(const float4*)(src + i);
    short4 o;
    o.x = f2bf(f.x); o.y = f2bf(f.y); o.z = f2bf(f.z); o.w = f2bf(f.w);
    *(short4*)(dst + i) = o;
}

// ---------------------------------------------------------------------------
// K1: fused qkv projection GEMM, 128x128 tile, 4 waves (2x2 of 64x64),
// 4x4 frag accumulators per wave. M=4096, N=768, K=1024, BK=64.
// N-tiles: [0,256)=q from xq; [256,512)=k, [512,768)=v from xkv.
__global__ __launch_bounds__(256) void k_gemm1(const short* __restrict__ xq,
                                               const short* __restrict__ xkv,
                                               const short* __restrict__ WcatT,
                                               short* __restrict__ pqk,
                                               short* __restrict__ vt){
    const int m0 = blockIdx.x * 128;
    const int n0 = blockIdx.y * 128;
    const short* X = (n0 < 256) ? xq : xkv;
    const int tid = threadIdx.x;
    const int wave = tid >> 6, lane = tid & 63, quad = lane >> 4, l16 = lane & 15;
    const int wrow = (wave & 1) * 64, wcol = (wave >> 1) * 64;
    const int r = tid >> 2, cc = (tid & 3) * 16;

    __shared__ short As[128][72];   // [m][k]
    __shared__ short Bs[128][72];   // [n][k]

    f32x4 acc[4][4];
    #pragma unroll
    for (int tm = 0; tm < 4; ++tm)
        #pragma unroll
        for (int tn = 0; tn < 4; ++tn) acc[tm][tn] = f32x4{0.f,0.f,0.f,0.f};

    for (int k0 = 0; k0 < 1024; k0 += 64) {
        const short* a0 = X + (size_t)(m0 + r) * 1024 + k0 + cc;
        const short* a1 = X + (size_t)(m0 + r + 64) * 1024 + k0 + cc;
        const short* b0 = WcatT + (size_t)(n0 + r) * 1024 + k0 + cc;
        const short* b1 = WcatT + (size_t)(n0 + r + 64) * 1024 + k0 + cc;
        *(bf16x8*)&As[r][cc]          = *(const bf16x8*)a0;
        *(bf16x8*)&As[r][cc + 8]      = *(const bf16x8*)(a0 + 8);
        *(bf16x8*)&As[r + 64][cc]     = *(const bf16x8*)a1;
        *(bf16x8*)&As[r + 64][cc + 8] = *(const bf16x8*)(a1 + 8);
        *(bf16x8*)&Bs[r][cc]          = *(const bf16x8*)b0;
        *(bf16x8*)&Bs[r][cc + 8]      = *(const bf16x8*)(b0 + 8);
        *(bf16x8*)&Bs[r + 64][cc]     = *(const bf16x8*)b1;
        *(bf16x8*)&Bs[r + 64][cc + 8] = *(const bf16x8*)(b1 + 8);
        __syncthreads();
        #pragma unroll
        for (int ks = 0; ks < 2; ++ks) {
            bf16x8 a[4];
            #pragma unroll
            for (int tm = 0; tm < 4; ++tm)
                a[tm] = *(bf16x8*)&As[wrow + tm * 16 + l16][ks * 32 + quad * 8];
            #pragma unroll
            for (int tn = 0; tn < 4; ++tn) {
                bf16x8 b = *(bf16x8*)&Bs[wcol + tn * 16 + l16][ks * 32 + quad * 8];
                #pragma unroll
                for (int tm = 0; tm < 4; ++tm)
                    acc[tm][tn] = __builtin_amdgcn_mfma_f32_16x16x32_bf16(a[tm], b, acc[tm][tn], 0, 0, 0);
            }
        }
        __syncthreads();
    }
    if (n0 < 512) {
        #pragma unroll
        for (int tm = 0; tm < 4; ++tm) {
            const int mrow = m0 + wrow + tm * 16 + quad * 4;
            #pragma unroll
            for (int tn = 0; tn < 4; ++tn) {
                const int col = n0 + wcol + tn * 16 + l16;
                #pragma unroll
                for (int rg = 0; rg < 4; ++rg)
                    pqk[(size_t)(mrow + rg) * 512 + col] = f2bf(acc[tm][tn][rg]);
            }
        }
    } else {
        #pragma unroll
        for (int tm = 0; tm < 4; ++tm) {
            const int mrow = m0 + wrow + tm * 16 + quad * 4;
            #pragma unroll
            for (int tn = 0; tn < 4; ++tn) {
                const int colv = n0 - 512 + wcol + tn * 16 + l16;
                const int vh = colv >> 6, d = colv & 63;
                #pragma unroll
                for (int rg = 0; rg < 4; ++rg) {
                    int m = mrow + rg, batch = m >> 11, s = m & 2047;
                    vt[((size_t)((batch * 4 + vh) * 64 + d)) * 2048 + s] = f2bf(acc[tm][tn][rg]);
                }
            }
        }
    }
}

// ---------------------------------------------------------------------------
// K2: split-K MFMA flash attention, no-max softmax (scores bounded; linear merge).
__global__ __launch_bounds__(256) void k_attn4(const short* __restrict__ pqk,
                                               const short* __restrict__ vt,
                                               float* __restrict__ Op,
                                               float* __restrict__ Lp,
                                               int nsplit){
    const int bx = blockIdx.x;
    const int qt = 31 - (bx / nsplit);
    const int s  = bx - (bx / nsplit) * nsplit;
    const int kv = blockIdx.y, batch = blockIdx.z;
    const int tid = threadIdx.x;
    const int wave = tid >> 6, lane = tid & 63, quad = lane >> 4, l16 = lane & 15;
    const int r = tid >> 2, c = (tid & 3) * 16;
    const int part = (((batch * 4 + kv) * 32 + qt) * nsplit + s);

    __shared__ short Ks[64][72];
    __shared__ short Vs[64][72];
    __shared__ short Ps[64][72];

    const size_t qrow = (size_t)(batch * SS + qt * 64 + wave * 16 + l16);
    bf16x8 aq0 = *(const bf16x8*)(pqk + qrow * 512 + kv * 64 + quad * 8);
    bf16x8 aq1 = *(const bf16x8*)(pqk + qrow * 512 + kv * 64 + 32 + quad * 8);

    f32x4 accO[4];
    #pragma unroll
    for (int t = 0; t < 4; ++t) accO[t] = f32x4{0.f, 0.f, 0.f, 0.f};
    float lrow[4] = {0.f, 0.f, 0.f, 0.f};

    bf16x8 rk0, rk1, rv0, rv1;
    int kt = s;
    if (kt <= qt) {
        const short* ksrc = pqk + (size_t)(batch * SS + kt * 64 + r) * 512 + 256 + kv * 64 + c;
        rk0 = *(const bf16x8*)ksrc; rk1 = *(const bf16x8*)(ksrc + 8);
        const short* vsrc = vt + ((size_t)((batch * 4 + kv) * 64 + r)) * 2048 + kt * 64 + c;
        rv0 = *(const bf16x8*)vsrc; rv1 = *(const bf16x8*)(vsrc + 8);
    }
    for (; kt <= qt; kt += nsplit) {
        *(bf16x8*)&Ks[r][c]     = rk0;
        *(bf16x8*)&Ks[r][c + 8] = rk1;
        *(bf16x8*)&Vs[r][c]     = rv0;
        *(bf16x8*)&Vs[r][c + 8] = rv1;
        __syncthreads();
        if (kt + nsplit <= qt) {
            const short* ksrc = pqk + (size_t)(batch * SS + (kt + nsplit) * 64 + r) * 512 + 256 + kv * 64 + c;
            rk0 = *(const bf16x8*)ksrc; rk1 = *(const bf16x8*)(ksrc + 8);
            const short* vsrc = vt + ((size_t)((batch * 4 + kv) * 64 + r)) * 2048 + (kt + nsplit) * 64 + c;
            rv0 = *(const bf16x8*)vsrc; rv1 = *(const bf16x8*)(vsrc + 8);
        }

        f32x4 sc[4];
        #pragma unroll
        for (int t = 0; t < 4; ++t) sc[t] = f32x4{0.f, 0.f, 0.f, 0.f};
        #pragma unroll
        for (int ks = 0; ks < 2; ++ks) {
            bf16x8 a = ks ? aq1 : aq0;
            #pragma unroll
            for (int t = 0; t < 4; ++t) {
                bf16x8 b = *(bf16x8*)&Ks[t * 16 + l16][ks * 32 + quad * 8];
                sc[t] = __builtin_amdgcn_mfma_f32_16x16x32_bf16(a, b, sc[t], 0, 0, 0);
            }
        }
        if (kt == qt) {
            #pragma unroll
            for (int t = 0; t < 4; ++t) {
                int colg = t * 16 + l16;
                #pragma unroll
                for (int rg = 0; rg < 4; ++rg)
                    if (colg > wave * 16 + quad * 4 + rg) sc[t][rg] = -1e30f;
            }
        }
        #pragma unroll
        for (int t = 0; t < 4; ++t) {
            #pragma unroll
            for (int rg = 0; rg < 4; ++rg) {
                float p = __expf(sc[t][rg]);
                lrow[rg] += p;
                Ps[wave * 16 + quad * 4 + rg][t * 16 + l16] = f2bf(p);
            }
        }
        #pragma unroll
        for (int ks = 0; ks < 2; ++ks) {
            bf16x8 ap = *(bf16x8*)&Ps[wave * 16 + l16][ks * 32 + quad * 8];
            #pragma unroll
            for (int t = 0; t < 4; ++t) {
                bf16x8 bv = *(bf16x8*)&Vs[t * 16 + l16][ks * 32 + quad * 8];
                accO[t] = __builtin_amdgcn_mfma_f32_16x16x32_bf16(ap, bv, accO[t], 0, 0, 0);
            }
        }
        __syncthreads();
    }
    #pragma unroll
    for (int rg = 0; rg < 4; ++rg) {
        float l = lrow[rg];
        l += __shfl_xor(l, 1);
        l += __shfl_xor(l, 2);
        l += __shfl_xor(l, 4);
        l += __shfl_xor(l, 8);
        lrow[rg] = l;
    }
    #pragma unroll
    for (int rg = 0; rg < 4; ++rg) {
        int row = wave * 16 + quad * 4 + rg;
        #pragma unroll
        for (int t = 0; t < 4; ++t)
            Op[(size_t)part * 4096 + row * 64 + t * 16 + l16] = accO[t][rg];
    }
    if (l16 == 0) {
        #pragma unroll
        for (int rg = 0; rg < 4; ++rg)
            Lp[part * 64 + (wave * 16 + quad * 4 + rg)] = lrow[rg];
    }
}

// K2b: linear merge of nsplit partials -> ao bf16 [4096][256]
__global__ __launch_bounds__(256) void k_combine(const float* __restrict__ Op,
                                                 const float* __restrict__ Lp,
                                                 short* __restrict__ ao,
                                                 int nsplit){
    const int qt = blockIdx.x, kv = blockIdx.y, batch = blockIdx.z;
    const int tid = threadIdx.x;
    const int rr = tid >> 2, cs = (tid & 3) * 16;
    const int pbase = ((batch * 4 + kv) * 32 + qt) * nsplit;
    float lsum = 0.f;
    for (int i = 0; i < nsplit; ++i) lsum += Lp[(pbase + i) * 64 + rr];
    float inv = 1.f / lsum;
    float o[16];
    #pragma unroll
    for (int j = 0; j < 16; ++j) o[j] = 0.f;
    for (int i = 0; i < nsplit; ++i) {
        const float* src = Op + (size_t)(pbase + i) * 4096 + rr * 64 + cs;
        #pragma unroll
        for (int j = 0; j < 16; j += 4) {
            float4 f = *(const float4*)(src + j);
            o[j] += f.x; o[j+1] += f.y; o[j+2] += f.z; o[j+3] += f.w;
        }
    }
    short* dst = ao + (size_t)(batch * SS + qt * 64 + rr) * 256 + kv * 64 + cs;
    #pragma unroll
    for (int j = 0; j < 16; ++j)
        dst[j] = f2bf(o[j] * inv);
}

// ---------------------------------------------------------------------------
// K3: output projection GEMM, 128x128 tile. M=4096, N=1024, K=256. fp32 out.
__global__ __launch_bounds__(256) void k_gemm2(const short* __restrict__ ao,
                                               const short* __restrict__ WoT,
                                               float* __restrict__ out){
    const int m0 = blockIdx.x * 128;
    const int n0 = blockIdx.y * 128;
    const int tid = threadIdx.x;
    const int wave = tid >> 6, lane = tid & 63, quad = lane >> 4, l16 = lane & 15;
    const int wrow = (wave & 1) * 64, wcol = (wave >> 1) * 64;
    const int r = tid >> 2, cc = (tid & 3) * 16;

    __shared__ short As[128][72];
    __shared__ short Bs[128][72];

    f32x4 acc[4][4];
    #pragma unroll
    for (int tm = 0; tm < 4; ++tm)
        #pragma unroll
        for (int tn = 0; tn < 4; ++tn) acc[tm][tn] = f32x4{0.f,0.f,0.f,0.f};

    for (int k0 = 0; k0 < 256; k0 += 64) {
        const short* a0 = ao + (size_t)(m0 + r) * 256 + k0 + cc;
        const short* a1 = ao + (size_t)(m0 + r + 64) * 256 + k0 + cc;
        const short* b0 = WoT + (size_t)(n0 + r) * 256 + k0 + cc;
        const short* b1 = WoT + (size_t)(n0 + r + 64) * 256 + k0 + cc;
        *(bf16x8*)&As[r][cc]          = *(const bf16x8*)a0;
        *(bf16x8*)&As[r][cc + 8]      = *(const bf16x8*)(a0 + 8);
        *(bf16x8*)&As[r + 64][cc]     = *(const bf16x8*)a1;
        *(bf16x8*)&As[r + 64][cc + 8] = *(const bf16x8*)(a1 + 8);
        *(bf16x8*)&Bs[r][cc]          = *(const bf16x8*)b0;
        *(bf16x8*)&Bs[r][cc + 8]      = *(const bf16x8*)(b0 + 8);
        *(bf16x8*)&Bs[r + 64][cc]     = *(const bf16x8*)b1;
        *(bf16x8*)&Bs[r + 64][cc + 8] = *(const bf16x8*)(b1 + 8);
        __syncthreads();
        #pragma unroll
        for (int ks = 0; ks < 2; ++ks) {
            bf16x8 a[4];
            #pragma unroll
            for (int tm = 0; tm < 4; ++tm)
                a[tm] = *(bf16x8*)&As[wrow + tm * 16 + l16][ks * 32 + quad * 8];
            #pragma unroll
            for (int tn = 0; tn < 4; ++tn) {
                bf16x8 b = *(bf16x8*)&Bs[wcol + tn * 16 + l16][ks * 32 + quad * 8];
                #pragma unroll
                for (int tm = 0; tm < 4; ++tm)
                    acc[tm][tn] = __builtin_amdgcn_mfma_f32_16x16x32_bf16(a[tm], b, acc[tm][tn], 0, 0, 0);
            }
        }
        __syncthreads();
    }
    #pragma unroll
    for (int tm = 0; tm < 4; ++tm) {
        const int mrow = m0 + wrow + tm * 16 + quad * 4;
        #pragma unroll
        for (int tn = 0; tn < 4; ++tn) {
            const int col = n0 + wcol + tn * 16 + l16;
            #pragma unroll
            for (int rg = 0; rg < 4; ++rg)
                out[(size_t)(mrow + rg) * 1024 + col] = acc[tm][tn][rg];
        }
    }
}

extern "C" void kernel_launch(void* const* d_in, const int* in_sizes, int n_in,
                              void* d_out, int out_size, void* d_ws, size_t ws_size,
                              hipStream_t stream) {
    const float* q_in  = (const float*)d_in[0];
    const float* kv_in = (const float*)d_in[1];
    int wqi = 3;
    for (int i = 2; i < n_in; ++i)
        if (in_sizes[i] == 1024 * 16 * 64) { wqi = i; break; }
    const float* Wq = (const float*)d_in[wqi];
    const float* Wk = (const float*)d_in[wqi + 1];
    const float* Wv = (const float*)d_in[wqi + 2];
    const float* Wo = (const float*)d_in[wqi + 3];
    float* out = (float*)d_out;

    // ws is ~256 MiB (R8/R9 profile: poison fill WRITE_SIZE = 262144 KB).
    // Static layout (high-water 50.4 MB), all disjoint:
    char* ws = (char*)d_ws;
    short* WcatT = (short*)(ws);                  // [0, 1.5M)
    short* WoT   = (short*)(ws + 1572864);        // [1.5M, 2M)
    short* ao    = (short*)(ws + 2097152);        // [2M, 4M)
    short* pqk   = (short*)(ws + 4194304);        // [4M, 8M)
    short* vt    = (short*)(ws + 8388608);        // [8M, 10M)
    float* Lp    = (float*)(ws + 10485760);       // [10M, +256K)
    short* xq    = (short*)(ws + 12582912);       // [12M, 20M)
    short* xkv   = (short*)(ws + 20971520);       // [20M, 28M)
    float* Op    = (float*)(ws + 33554432);       // [32M, 48M)
    const int nsplit = 4;

    hipLaunchKernelGGL(k_prep_w,  dim3(256),     dim3(256), 0, stream,
                       Wq, Wk, Wv, Wo, WcatT, WoT);
    hipLaunchKernelGGL(k_prep_x,  dim3(4096, 2), dim3(256), 0, stream,
                       q_in, kv_in, xq, xkv);
    hipLaunchKernelGGL(k_gemm1,   dim3(32, 6),   dim3(256), 0, stream,
                       xq, xkv, WcatT, pqk, vt);
    hipLaunchKernelGGL(k_attn4,   dim3(32 * nsplit, 4, 2), dim3(256), 0, stream,
                       pqk, vt, Op, Lp, nsplit);
    hipLaunchKernelGGL(k_combine, dim3(32, 4, 2), dim3(256), 0, stream,
                       Op, Lp, ao, nsplit);
    hipLaunchKernelGGL(k_gemm2,   dim3(32, 8),   dim3(256), 0, stream,
                       ao, WoT, out);
}

// Round 11
// 161.153 us; speedup vs baseline: 1.0278x; 1.0278x over previous
//
#include <hip/hip_runtime.h>
#include <hip/hip_bf16.h>

#define SS 2048

typedef __attribute__((ext_vector_type(8))) short bf16x8;
typedef __attribute__((ext_vector_type(4))) float f32x4;

__device__ __forceinline__ short f2bf(float f){
    unsigned u = __float_as_uint(f);
    u += 0x7fff + ((u >> 16) & 1);   // RNE; inputs finite
    return (short)(u >> 16);
}

// ---------------------------------------------------------------------------
// K0: weight prep with coalesced reads + LDS transpose.
// blocks 0..191: WcatT[768][1024]  (q:0.125*group-sum | k | v), bf16, B^T layout
// blocks 192..255: WoT[1024][256] = Wo^T, bf16
__global__ __launch_bounds__(256) void k_prep_w(const float* __restrict__ Wq,
                                                const float* __restrict__ Wk,
                                                const float* __restrict__ Wv,
                                                const float* __restrict__ Wo,
                                                short* __restrict__ WcatT,
                                                short* __restrict__ WoT){
    __shared__ float Ts[64][65];
    const int bx = blockIdx.x;
    const int r  = threadIdx.x >> 2;
    const int cq = (threadIdx.x & 3) * 16;
    if (bx < 192) {
        const int ktile = bx & 15, ntile = bx >> 4;
        const int k0 = ktile * 64, n0 = ntile * 64;
        if (ntile < 4) {
            const float* base = Wq + (size_t)(k0 + r) * 1024 + ntile * 256;
            #pragma unroll
            for (int i = 0; i < 16; i += 4) {
                float4 a = *(const float4*)(base + cq + i);
                float4 b = *(const float4*)(base + 64 + cq + i);
                float4 c = *(const float4*)(base + 128 + cq + i);
                float4 d = *(const float4*)(base + 192 + cq + i);
                Ts[r][cq+i]   = 0.125f * (a.x + b.x + c.x + d.x);
                Ts[r][cq+i+1] = 0.125f * (a.y + b.y + c.y + d.y);
                Ts[r][cq+i+2] = 0.125f * (a.z + b.z + c.z + d.z);
                Ts[r][cq+i+3] = 0.125f * (a.w + b.w + c.w + d.w);
            }
        } else {
            const float* W = (ntile < 8) ? Wk : Wv;
            const float* base = W + (size_t)(k0 + r) * 256 + (ntile & 3) * 64;
            #pragma unroll
            for (int i = 0; i < 16; i += 4) {
                float4 a = *(const float4*)(base + cq + i);
                Ts[r][cq+i] = a.x; Ts[r][cq+i+1] = a.y;
                Ts[r][cq+i+2] = a.z; Ts[r][cq+i+3] = a.w;
            }
        }
        __syncthreads();
        short tmp[16];
        #pragma unroll
        for (int i = 0; i < 16; ++i) tmp[i] = f2bf(Ts[cq+i][r]);
        short* dst = WcatT + (size_t)(n0 + r) * 1024 + k0 + cq;
        *(bf16x8*)dst       = *(bf16x8*)&tmp[0];
        *(bf16x8*)(dst + 8) = *(bf16x8*)&tmp[8];
    } else {
        const int b2 = bx - 192;
        const int ktile = b2 & 3, ntile = b2 >> 2;
        const int k0 = ktile * 64, n0 = ntile * 64;
        const float* base = Wo + (size_t)(k0 + r) * 1024 + n0;
        #pragma unroll
        for (int i = 0; i < 16; i += 4) {
            float4 a = *(const float4*)(base + cq + i);
            Ts[r][cq+i] = a.x; Ts[r][cq+i+1] = a.y;
            Ts[r][cq+i+2] = a.z; Ts[r][cq+i+3] = a.w;
        }
        __syncthreads();
        short tmp[16];
        #pragma unroll
        for (int i = 0; i < 16; ++i) tmp[i] = f2bf(Ts[cq+i][r]);
        short* dst = WoT + (size_t)(n0 + r) * 256 + k0 + cq;
        *(bf16x8*)dst       = *(bf16x8*)&tmp[0];
        *(bf16x8*)(dst + 8) = *(bf16x8*)&tmp[8];
    }
}

// ---------------------------------------------------------------------------
// K1: fused qkv projection GEMM, 128x128 tile, 4 waves, 4x4 frags.
// A staged inline from fp32 (R5-proven), register-prefetched next tile.
__global__ __launch_bounds__(256) void k_gemm1(const float* __restrict__ q_in,
                                               const float* __restrict__ kv_in,
                                               const short* __restrict__ WcatT,
                                               short* __restrict__ pqk,
                                               short* __restrict__ vt){
    const int m0 = blockIdx.x * 128;
    const int n0 = blockIdx.y * 128;
    const float* X = (n0 < 256) ? q_in : kv_in;
    const int tid = threadIdx.x;
    const int wave = tid >> 6, lane = tid & 63, quad = lane >> 4, l16 = lane & 15;
    const int wrow = (wave & 1) * 64, wcol = (wave >> 1) * 64;
    const int r = tid >> 2, cc = (tid & 3) * 16;

    __shared__ short As[128][72];
    __shared__ short Bs[128][72];

    f32x4 acc[4][4];
    #pragma unroll
    for (int tm = 0; tm < 4; ++tm)
        #pragma unroll
        for (int tn = 0; tn < 4; ++tn) acc[tm][tn] = f32x4{0.f,0.f,0.f,0.f};

    short ta0[16], ta1[16];
    bf16x8 rb0, rb1, rb2, rb3;
    {
        const float* a0 = X + (size_t)(m0 + r) * 1024 + cc;
        const float* a1 = a0 + (size_t)64 * 1024;
        #pragma unroll
        for (int i = 0; i < 16; i += 4) {
            float4 f = *(const float4*)(a0 + i);
            ta0[i] = f2bf(f.x); ta0[i+1] = f2bf(f.y); ta0[i+2] = f2bf(f.z); ta0[i+3] = f2bf(f.w);
            float4 g = *(const float4*)(a1 + i);
            ta1[i] = f2bf(g.x); ta1[i+1] = f2bf(g.y); ta1[i+2] = f2bf(g.z); ta1[i+3] = f2bf(g.w);
        }
        const short* b0 = WcatT + (size_t)(n0 + r) * 1024 + cc;
        const short* b1 = b0 + (size_t)64 * 1024;
        rb0 = *(const bf16x8*)b0; rb1 = *(const bf16x8*)(b0 + 8);
        rb2 = *(const bf16x8*)b1; rb3 = *(const bf16x8*)(b1 + 8);
    }

    for (int k0 = 0; k0 < 1024; k0 += 64) {
        *(bf16x8*)&As[r][cc]          = *(bf16x8*)&ta0[0];
        *(bf16x8*)&As[r][cc + 8]      = *(bf16x8*)&ta0[8];
        *(bf16x8*)&As[r + 64][cc]     = *(bf16x8*)&ta1[0];
        *(bf16x8*)&As[r + 64][cc + 8] = *(bf16x8*)&ta1[8];
        *(bf16x8*)&Bs[r][cc]          = rb0;
        *(bf16x8*)&Bs[r][cc + 8]      = rb1;
        *(bf16x8*)&Bs[r + 64][cc]     = rb2;
        *(bf16x8*)&Bs[r + 64][cc + 8] = rb3;
        __syncthreads();
        if (k0 + 64 < 1024) {   // prefetch next K-tile (overlaps MFMA)
            const float* a0 = X + (size_t)(m0 + r) * 1024 + k0 + 64 + cc;
            const float* a1 = a0 + (size_t)64 * 1024;
            #pragma unroll
            for (int i = 0; i < 16; i += 4) {
                float4 f = *(const float4*)(a0 + i);
                ta0[i] = f2bf(f.x); ta0[i+1] = f2bf(f.y); ta0[i+2] = f2bf(f.z); ta0[i+3] = f2bf(f.w);
                float4 g = *(const float4*)(a1 + i);
                ta1[i] = f2bf(g.x); ta1[i+1] = f2bf(g.y); ta1[i+2] = f2bf(g.z); ta1[i+3] = f2bf(g.w);
            }
            const short* b0 = WcatT + (size_t)(n0 + r) * 1024 + k0 + 64 + cc;
            const short* b1 = b0 + (size_t)64 * 1024;
            rb0 = *(const bf16x8*)b0; rb1 = *(const bf16x8*)(b0 + 8);
            rb2 = *(const bf16x8*)b1; rb3 = *(const bf16x8*)(b1 + 8);
        }
        #pragma unroll
        for (int ks = 0; ks < 2; ++ks) {
            bf16x8 a[4];
            #pragma unroll
            for (int tm = 0; tm < 4; ++tm)
                a[tm] = *(bf16x8*)&As[wrow + tm * 16 + l16][ks * 32 + quad * 8];
            #pragma unroll
            for (int tn = 0; tn < 4; ++tn) {
                bf16x8 b = *(bf16x8*)&Bs[wcol + tn * 16 + l16][ks * 32 + quad * 8];
                #pragma unroll
                for (int tm = 0; tm < 4; ++tm)
                    acc[tm][tn] = __builtin_amdgcn_mfma_f32_16x16x32_bf16(a[tm], b, acc[tm][tn], 0, 0, 0);
            }
        }
        __syncthreads();
    }
    if (n0 < 512) {
        #pragma unroll
        for (int tm = 0; tm < 4; ++tm) {
            const int mrow = m0 + wrow + tm * 16 + quad * 4;
            #pragma unroll
            for (int tn = 0; tn < 4; ++tn) {
                const int col = n0 + wcol + tn * 16 + l16;
                #pragma unroll
                for (int rg = 0; rg < 4; ++rg)
                    pqk[(size_t)(mrow + rg) * 512 + col] = f2bf(acc[tm][tn][rg]);
            }
        }
    } else {
        #pragma unroll
        for (int tm = 0; tm < 4; ++tm) {
            const int mrow = m0 + wrow + tm * 16 + quad * 4;
            #pragma unroll
            for (int tn = 0; tn < 4; ++tn) {
                const int colv = n0 - 512 + wcol + tn * 16 + l16;
                const int vh = colv >> 6, d = colv & 63;
                #pragma unroll
                for (int rg = 0; rg < 4; ++rg) {
                    int m = mrow + rg, batch = m >> 11, s = m & 2047;
                    vt[((size_t)((batch * 4 + vh) * 64 + d)) * 2048 + s] = f2bf(acc[tm][tn][rg]);
                }
            }
        }
    }
}

// ---------------------------------------------------------------------------
// K2: split-K MFMA flash attention, no-max softmax (bounded scores, linear merge).
__global__ __launch_bounds__(256) void k_attn4(const short* __restrict__ pqk,
                                               const short* __restrict__ vt,
                                               float* __restrict__ Op,
                                               float* __restrict__ Lp,
                                               int nsplit){
    const int bx = blockIdx.x;
    const int qt = 31 - (bx / nsplit);
    const int s  = bx - (bx / nsplit) * nsplit;
    const int kv = blockIdx.y, batch = blockIdx.z;
    const int tid = threadIdx.x;
    const int wave = tid >> 6, lane = tid & 63, quad = lane >> 4, l16 = lane & 15;
    const int r = tid >> 2, c = (tid & 3) * 16;
    const int part = (((batch * 4 + kv) * 32 + qt) * nsplit + s);

    __shared__ short Ks[64][72];
    __shared__ short Vs[64][72];
    __shared__ short Ps[64][72];

    const size_t qrow = (size_t)(batch * SS + qt * 64 + wave * 16 + l16);
    bf16x8 aq0 = *(const bf16x8*)(pqk + qrow * 512 + kv * 64 + quad * 8);
    bf16x8 aq1 = *(const bf16x8*)(pqk + qrow * 512 + kv * 64 + 32 + quad * 8);

    f32x4 accO[4];
    #pragma unroll
    for (int t = 0; t < 4; ++t) accO[t] = f32x4{0.f, 0.f, 0.f, 0.f};
    float lrow[4] = {0.f, 0.f, 0.f, 0.f};

    bf16x8 rk0, rk1, rv0, rv1;
    int kt = s;
    if (kt <= qt) {
        const short* ksrc = pqk + (size_t)(batch * SS + kt * 64 + r) * 512 + 256 + kv * 64 + c;
        rk0 = *(const bf16x8*)ksrc; rk1 = *(const bf16x8*)(ksrc + 8);
        const short* vsrc = vt + ((size_t)((batch * 4 + kv) * 64 + r)) * 2048 + kt * 64 + c;
        rv0 = *(const bf16x8*)vsrc; rv1 = *(const bf16x8*)(vsrc + 8);
    }
    for (; kt <= qt; kt += nsplit) {
        *(bf16x8*)&Ks[r][c]     = rk0;
        *(bf16x8*)&Ks[r][c + 8] = rk1;
        *(bf16x8*)&Vs[r][c]     = rv0;
        *(bf16x8*)&Vs[r][c + 8] = rv1;
        __syncthreads();
        if (kt + nsplit <= qt) {
            const short* ksrc = pqk + (size_t)(batch * SS + (kt + nsplit) * 64 + r) * 512 + 256 + kv * 64 + c;
            rk0 = *(const bf16x8*)ksrc; rk1 = *(const bf16x8*)(ksrc + 8);
            const short* vsrc = vt + ((size_t)((batch * 4 + kv) * 64 + r)) * 2048 + (kt + nsplit) * 64 + c;
            rv0 = *(const bf16x8*)vsrc; rv1 = *(const bf16x8*)(vsrc + 8);
        }

        f32x4 sc[4];
        #pragma unroll
        for (int t = 0; t < 4; ++t) sc[t] = f32x4{0.f, 0.f, 0.f, 0.f};
        #pragma unroll
        for (int ks = 0; ks < 2; ++ks) {
            bf16x8 a = ks ? aq1 : aq0;
            #pragma unroll
            for (int t = 0; t < 4; ++t) {
                bf16x8 b = *(bf16x8*)&Ks[t * 16 + l16][ks * 32 + quad * 8];
                sc[t] = __builtin_amdgcn_mfma_f32_16x16x32_bf16(a, b, sc[t], 0, 0, 0);
            }
        }
        if (kt == qt) {
            #pragma unroll
            for (int t = 0; t < 4; ++t) {
                int colg = t * 16 + l16;
                #pragma unroll
                for (int rg = 0; rg < 4; ++rg)
                    if (colg > wave * 16 + quad * 4 + rg) sc[t][rg] = -1e30f;
            }
        }
        #pragma unroll
        for (int t = 0; t < 4; ++t) {
            #pragma unroll
            for (int rg = 0; rg < 4; ++rg) {
                float p = __expf(sc[t][rg]);
                lrow[rg] += p;
                Ps[wave * 16 + quad * 4 + rg][t * 16 + l16] = f2bf(p);
            }
        }
        #pragma unroll
        for (int ks = 0; ks < 2; ++ks) {
            bf16x8 ap = *(bf16x8*)&Ps[wave * 16 + l16][ks * 32 + quad * 8];
            #pragma unroll
            for (int t = 0; t < 4; ++t) {
                bf16x8 bv = *(bf16x8*)&Vs[t * 16 + l16][ks * 32 + quad * 8];
                accO[t] = __builtin_amdgcn_mfma_f32_16x16x32_bf16(ap, bv, accO[t], 0, 0, 0);
            }
        }
        __syncthreads();
    }
    #pragma unroll
    for (int rg = 0; rg < 4; ++rg) {
        float l = lrow[rg];
        l += __shfl_xor(l, 1);
        l += __shfl_xor(l, 2);
        l += __shfl_xor(l, 4);
        l += __shfl_xor(l, 8);
        lrow[rg] = l;
    }
    #pragma unroll
    for (int rg = 0; rg < 4; ++rg) {
        int row = wave * 16 + quad * 4 + rg;
        #pragma unroll
        for (int t = 0; t < 4; ++t)
            Op[(size_t)part * 4096 + row * 64 + t * 16 + l16] = accO[t][rg];
    }
    if (l16 == 0) {
        #pragma unroll
        for (int rg = 0; rg < 4; ++rg)
            Lp[part * 64 + (wave * 16 + quad * 4 + rg)] = lrow[rg];
    }
}

// K2b: linear merge of nsplit partials -> ao bf16 [4096][256]
__global__ __launch_bounds__(256) void k_combine(const float* __restrict__ Op,
                                                 const float* __restrict__ Lp,
                                                 short* __restrict__ ao,
                                                 int nsplit){
    const int qt = blockIdx.x, kv = blockIdx.y, batch = blockIdx.z;
    const int tid = threadIdx.x;
    const int rr = tid >> 2, cs = (tid & 3) * 16;
    const int pbase = ((batch * 4 + kv) * 32 + qt) * nsplit;
    float lsum = 0.f;
    for (int i = 0; i < nsplit; ++i) lsum += Lp[(pbase + i) * 64 + rr];
    float inv = 1.f / lsum;
    float o[16];
    #pragma unroll
    for (int j = 0; j < 16; ++j) o[j] = 0.f;
    for (int i = 0; i < nsplit; ++i) {
        const float* src = Op + (size_t)(pbase + i) * 4096 + rr * 64 + cs;
        #pragma unroll
        for (int j = 0; j < 16; j += 4) {
            float4 f = *(const float4*)(src + j);
            o[j] += f.x; o[j+1] += f.y; o[j+2] += f.z; o[j+3] += f.w;
        }
    }
    short* dst = ao + (size_t)(batch * SS + qt * 64 + rr) * 256 + kv * 64 + cs;
    #pragma unroll
    for (int j = 0; j < 16; ++j)
        dst[j] = f2bf(o[j] * inv);
}

// ---------------------------------------------------------------------------
// K3: output projection GEMM, 128x128 tile, register-prefetched. fp32 out.
__global__ __launch_bounds__(256) void k_gemm2(const short* __restrict__ ao,
                                               const short* __restrict__ WoT,
                                               float* __restrict__ out){
    const int m0 = blockIdx.x * 128;
    const int n0 = blockIdx.y * 128;
    const int tid = threadIdx.x;
    const int wave = tid >> 6, lane = tid & 63, quad = lane >> 4, l16 = lane & 15;
    const int wrow = (wave & 1) * 64, wcol = (wave >> 1) * 64;
    const int r = tid >> 2, cc = (tid & 3) * 16;

    __shared__ short As[128][72];
    __shared__ short Bs[128][72];

    f32x4 acc[4][4];
    #pragma unroll
    for (int tm = 0; tm < 4; ++tm)
        #pragma unroll
        for (int tn = 0; tn < 4; ++tn) acc[tm][tn] = f32x4{0.f,0.f,0.f,0.f};

    bf16x8 ra0, ra1, ra2, ra3, rb0, rb1, rb2, rb3;
    {
        const short* a0 = ao + (size_t)(m0 + r) * 256 + cc;
        const short* a1 = a0 + (size_t)64 * 256;
        const short* b0 = WoT + (size_t)(n0 + r) * 256 + cc;
        const short* b1 = b0 + (size_t)64 * 256;
        ra0 = *(const bf16x8*)a0; ra1 = *(const bf16x8*)(a0 + 8);
        ra2 = *(const bf16x8*)a1; ra3 = *(const bf16x8*)(a1 + 8);
        rb0 = *(const bf16x8*)b0; rb1 = *(const bf16x8*)(b0 + 8);
        rb2 = *(const bf16x8*)b1; rb3 = *(const bf16x8*)(b1 + 8);
    }
    for (int k0 = 0; k0 < 256; k0 += 64) {
        *(bf16x8*)&As[r][cc]          = ra0;
        *(bf16x8*)&As[r][cc + 8]      = ra1;
        *(bf16x8*)&As[r + 64][cc]     = ra2;
        *(bf16x8*)&As[r + 64][cc + 8] = ra3;
        *(bf16x8*)&Bs[r][cc]          = rb0;
        *(bf16x8*)&Bs[r][cc + 8]      = rb1;
        *(bf16x8*)&Bs[r + 64][cc]     = rb2;
        *(bf16x8*)&Bs[r + 64][cc + 8] = rb3;
        __syncthreads();
        if (k0 + 64 < 256) {
            const short* a0 = ao + (size_t)(m0 + r) * 256 + k0 + 64 + cc;
            const short* a1 = a0 + (size_t)64 * 256;
            const short* b0 = WoT + (size_t)(n0 + r) * 256 + k0 + 64 + cc;
            const short* b1 = b0 + (size_t)64 * 256;
            ra0 = *(const bf16x8*)a0; ra1 = *(const bf16x8*)(a0 + 8);
            ra2 = *(const bf16x8*)a1; ra3 = *(const bf16x8*)(a1 + 8);
            rb0 = *(const bf16x8*)b0; rb1 = *(const bf16x8*)(b0 + 8);
            rb2 = *(const bf16x8*)b1; rb3 = *(const bf16x8*)(b1 + 8);
        }
        #pragma unroll
        for (int ks = 0; ks < 2; ++ks) {
            bf16x8 a[4];
            #pragma unroll
            for (int tm = 0; tm < 4; ++tm)
                a[tm] = *(bf16x8*)&As[wrow + tm * 16 + l16][ks * 32 + quad * 8];
            #pragma unroll
            for (int tn = 0; tn < 4; ++tn) {
                bf16x8 b = *(bf16x8*)&Bs[wcol + tn * 16 + l16][ks * 32 + quad * 8];
                #pragma unroll
                for (int tm = 0; tm < 4; ++tm)
                    acc[tm][tn] = __builtin_amdgcn_mfma_f32_16x16x32_bf16(a[tm], b, acc[tm][tn], 0, 0, 0);
            }
        }
        __syncthreads();
    }
    #pragma unroll
    for (int tm = 0; tm < 4; ++tm) {
        const int mrow = m0 + wrow + tm * 16 + quad * 4;
        #pragma unroll
        for (int tn = 0; tn < 4; ++tn) {
            const int col = n0 + wcol + tn * 16 + l16;
            #pragma unroll
            for (int rg = 0; rg < 4; ++rg)
                out[(size_t)(mrow + rg) * 1024 + col] = acc[tm][tn][rg];
        }
    }
}

extern "C" void kernel_launch(void* const* d_in, const int* in_sizes, int n_in,
                              void* d_out, int out_size, void* d_ws, size_t ws_size,
                              hipStream_t stream) {
    const float* q_in  = (const float*)d_in[0];
    const float* kv_in = (const float*)d_in[1];
    int wqi = 3;
    for (int i = 2; i < n_in; ++i)
        if (in_sizes[i] == 1024 * 16 * 64) { wqi = i; break; }
    const float* Wq = (const float*)d_in[wqi];
    const float* Wk = (const float*)d_in[wqi + 1];
    const float* Wv = (const float*)d_in[wqi + 2];
    const float* Wo = (const float*)d_in[wqi + 3];
    float* out = (float*)d_out;

    // ws is ~256 MiB (R8-R10 profile). Static disjoint layout, high-water 66 MB:
    char* ws = (char*)d_ws;
    short* WcatT = (short*)(ws);                  // [0, 1.5M)
    short* WoT   = (short*)(ws + 1572864);        // [1.5M, 2M)
    short* ao    = (short*)(ws + 2097152);        // [2M, 4M)
    short* pqk   = (short*)(ws + 4194304);        // [4M, 8M)
    short* vt    = (short*)(ws + 8388608);        // [8M, 10M)
    float* Lp    = (float*)(ws + 10485760);       // [10M, +512K)
    float* Op    = (float*)(ws + 33554432);       // [32M, 64M) @ nsplit=8
    const int nsplit = 8;

    hipLaunchKernelGGL(k_prep_w,  dim3(256),     dim3(256), 0, stream,
                       Wq, Wk, Wv, Wo, WcatT, WoT);
    hipLaunchKernelGGL(k_gemm1,   dim3(32, 6),   dim3(256), 0, stream,
                       q_in, kv_in, WcatT, pqk, vt);
    hipLaunchKernelGGL(k_attn4,   dim3(32 * nsplit, 4, 2), dim3(256), 0, stream,
                       pqk, vt, Op, Lp, nsplit);
    hipLaunchKernelGGL(k_combine, dim3(32, 4, 2), dim3(256), 0, stream,
                       Op, Lp, ao, nsplit);
    hipLaunchKernelGGL(k_gemm2,   dim3(32, 8),   dim3(256), 0, stream,
                       ao, WoT, out);
}

// Round 12
// 158.781 us; speedup vs baseline: 1.0432x; 1.0149x over previous
//
#include <hip/hip_runtime.h>
#include <hip/hip_bf16.h>

#define SS 2048
#define NSPLIT 8

typedef __attribute__((ext_vector_type(8))) short bf16x8;
typedef __attribute__((ext_vector_type(4))) float f32x4;

__device__ __forceinline__ short f2bf(float f){
    unsigned u = __float_as_uint(f);
    u += 0x7fff + ((u >> 16) & 1);   // RNE; inputs finite
    return (short)(u >> 16);
}
__device__ __forceinline__ float bf2f(short s){
    return __uint_as_float(((unsigned)(unsigned short)s) << 16);
}

// ---------------------------------------------------------------------------
// K0: weight prep with coalesced reads + LDS transpose.
// blocks 0..191: WcatT[768][1024]  (q:0.125*group-sum | k | v), bf16, B^T layout
// blocks 192..255: WoT[1024][256] = Wo^T, bf16
__global__ __launch_bounds__(256) void k_prep_w(const float* __restrict__ Wq,
                                                const float* __restrict__ Wk,
                                                const float* __restrict__ Wv,
                                                const float* __restrict__ Wo,
                                                short* __restrict__ WcatT,
                                                short* __restrict__ WoT){
    __shared__ float Ts[64][65];
    const int bx = blockIdx.x;
    const int r  = threadIdx.x >> 2;
    const int cq = (threadIdx.x & 3) * 16;
    if (bx < 192) {
        const int ktile = bx & 15, ntile = bx >> 4;
        const int k0 = ktile * 64, n0 = ntile * 64;
        if (ntile < 4) {
            const float* base = Wq + (size_t)(k0 + r) * 1024 + ntile * 256;
            #pragma unroll
            for (int i = 0; i < 16; i += 4) {
                float4 a = *(const float4*)(base + cq + i);
                float4 b = *(const float4*)(base + 64 + cq + i);
                float4 c = *(const float4*)(base + 128 + cq + i);
                float4 d = *(const float4*)(base + 192 + cq + i);
                Ts[r][cq+i]   = 0.125f * (a.x + b.x + c.x + d.x);
                Ts[r][cq+i+1] = 0.125f * (a.y + b.y + c.y + d.y);
                Ts[r][cq+i+2] = 0.125f * (a.z + b.z + c.z + d.z);
                Ts[r][cq+i+3] = 0.125f * (a.w + b.w + c.w + d.w);
            }
        } else {
            const float* W = (ntile < 8) ? Wk : Wv;
            const float* base = W + (size_t)(k0 + r) * 256 + (ntile & 3) * 64;
            #pragma unroll
            for (int i = 0; i < 16; i += 4) {
                float4 a = *(const float4*)(base + cq + i);
                Ts[r][cq+i] = a.x; Ts[r][cq+i+1] = a.y;
                Ts[r][cq+i+2] = a.z; Ts[r][cq+i+3] = a.w;
            }
        }
        __syncthreads();
        short tmp[16];
        #pragma unroll
        for (int i = 0; i < 16; ++i) tmp[i] = f2bf(Ts[cq+i][r]);
        short* dst = WcatT + (size_t)(n0 + r) * 1024 + k0 + cq;
        *(bf16x8*)dst       = *(bf16x8*)&tmp[0];
        *(bf16x8*)(dst + 8) = *(bf16x8*)&tmp[8];
    } else {
        const int b2 = bx - 192;
        const int ktile = b2 & 3, ntile = b2 >> 2;
        const int k0 = ktile * 64, n0 = ntile * 64;
        const float* base = Wo + (size_t)(k0 + r) * 1024 + n0;
        #pragma unroll
        for (int i = 0; i < 16; i += 4) {
            float4 a = *(const float4*)(base + cq + i);
            Ts[r][cq+i] = a.x; Ts[r][cq+i+1] = a.y;
            Ts[r][cq+i+2] = a.z; Ts[r][cq+i+3] = a.w;
        }
        __syncthreads();
        short tmp[16];
        #pragma unroll
        for (int i = 0; i < 16; ++i) tmp[i] = f2bf(Ts[cq+i][r]);
        short* dst = WoT + (size_t)(n0 + r) * 256 + k0 + cq;
        *(bf16x8*)dst       = *(bf16x8*)&tmp[0];
        *(bf16x8*)(dst + 8) = *(bf16x8*)&tmp[8];
    }
}

// ---------------------------------------------------------------------------
// K1: fused qkv projection GEMM, 128x128 tile, 4 waves, 4x4 frags.
// A staged inline from fp32; register prefetch of next K-tile.
// v-epilogue transposes through LDS so vt stores are contiguous 128B runs
// (old path: 2B stores at 4KB stride — write-allocate pathology).
#define AS(r, c) SMEM[(r) * 72 + (c)]
#define BS(r, c) SMEM[128 * 72 + (r) * 72 + (c)]
__global__ __launch_bounds__(256) void k_gemm1(const float* __restrict__ q_in,
                                               const float* __restrict__ kv_in,
                                               const short* __restrict__ WcatT,
                                               short* __restrict__ pqk,
                                               short* __restrict__ vt){
    const int m0 = blockIdx.x * 128;
    const int n0 = blockIdx.y * 128;
    const float* X = (n0 < 256) ? q_in : kv_in;
    const int tid = threadIdx.x;
    const int wave = tid >> 6, lane = tid & 63, quad = lane >> 4, l16 = lane & 15;
    const int wrow = (wave & 1) * 64, wcol = (wave >> 1) * 64;
    const int r = tid >> 2, cc = (tid & 3) * 16;

    __shared__ short SMEM[2 * 128 * 72];   // As|Bs during K-loop; Tt in epilogue

    f32x4 acc[4][4];
    #pragma unroll
    for (int tm = 0; tm < 4; ++tm)
        #pragma unroll
        for (int tn = 0; tn < 4; ++tn) acc[tm][tn] = f32x4{0.f,0.f,0.f,0.f};

    short ta0[16], ta1[16];
    bf16x8 rb0, rb1, rb2, rb3;
    {
        const float* a0 = X + (size_t)(m0 + r) * 1024 + cc;
        const float* a1 = a0 + (size_t)64 * 1024;
        #pragma unroll
        for (int i = 0; i < 16; i += 4) {
            float4 f = *(const float4*)(a0 + i);
            ta0[i] = f2bf(f.x); ta0[i+1] = f2bf(f.y); ta0[i+2] = f2bf(f.z); ta0[i+3] = f2bf(f.w);
            float4 g = *(const float4*)(a1 + i);
            ta1[i] = f2bf(g.x); ta1[i+1] = f2bf(g.y); ta1[i+2] = f2bf(g.z); ta1[i+3] = f2bf(g.w);
        }
        const short* b0 = WcatT + (size_t)(n0 + r) * 1024 + cc;
        const short* b1 = b0 + (size_t)64 * 1024;
        rb0 = *(const bf16x8*)b0; rb1 = *(const bf16x8*)(b0 + 8);
        rb2 = *(const bf16x8*)b1; rb3 = *(const bf16x8*)(b1 + 8);
    }

    for (int k0 = 0; k0 < 1024; k0 += 64) {
        *(bf16x8*)&AS(r, cc)          = *(bf16x8*)&ta0[0];
        *(bf16x8*)&AS(r, cc + 8)      = *(bf16x8*)&ta0[8];
        *(bf16x8*)&AS(r + 64, cc)     = *(bf16x8*)&ta1[0];
        *(bf16x8*)&AS(r + 64, cc + 8) = *(bf16x8*)&ta1[8];
        *(bf16x8*)&BS(r, cc)          = rb0;
        *(bf16x8*)&BS(r, cc + 8)      = rb1;
        *(bf16x8*)&BS(r + 64, cc)     = rb2;
        *(bf16x8*)&BS(r + 64, cc + 8) = rb3;
        __syncthreads();
        if (k0 + 64 < 1024) {
            const float* a0 = X + (size_t)(m0 + r) * 1024 + k0 + 64 + cc;
            const float* a1 = a0 + (size_t)64 * 1024;
            #pragma unroll
            for (int i = 0; i < 16; i += 4) {
                float4 f = *(const float4*)(a0 + i);
                ta0[i] = f2bf(f.x); ta0[i+1] = f2bf(f.y); ta0[i+2] = f2bf(f.z); ta0[i+3] = f2bf(f.w);
                float4 g = *(const float4*)(a1 + i);
                ta1[i] = f2bf(g.x); ta1[i+1] = f2bf(g.y); ta1[i+2] = f2bf(g.z); ta1[i+3] = f2bf(g.w);
            }
            const short* b0 = WcatT + (size_t)(n0 + r) * 1024 + k0 + 64 + cc;
            const short* b1 = b0 + (size_t)64 * 1024;
            rb0 = *(const bf16x8*)b0; rb1 = *(const bf16x8*)(b0 + 8);
            rb2 = *(const bf16x8*)b1; rb3 = *(const bf16x8*)(b1 + 8);
        }
        #pragma unroll
        for (int ks = 0; ks < 2; ++ks) {
            bf16x8 a[4];
            #pragma unroll
            for (int tm = 0; tm < 4; ++tm)
                a[tm] = *(bf16x8*)&AS(wrow + tm * 16 + l16, ks * 32 + quad * 8);
            #pragma unroll
            for (int tn = 0; tn < 4; ++tn) {
                bf16x8 b = *(bf16x8*)&BS(wcol + tn * 16 + l16, ks * 32 + quad * 8);
                #pragma unroll
                for (int tm = 0; tm < 4; ++tm)
                    acc[tm][tn] = __builtin_amdgcn_mfma_f32_16x16x32_bf16(a[tm], b, acc[tm][tn], 0, 0, 0);
            }
        }
        __syncthreads();
    }
    if (n0 < 512) {
        #pragma unroll
        for (int tm = 0; tm < 4; ++tm) {
            const int mrow = m0 + wrow + tm * 16 + quad * 4;
            #pragma unroll
            for (int tn = 0; tn < 4; ++tn) {
                const int col = n0 + wcol + tn * 16 + l16;
                #pragma unroll
                for (int rg = 0; rg < 4; ++rg)
                    pqk[(size_t)(mrow + rg) * 512 + col] = f2bf(acc[tm][tn][rg]);
            }
        }
    } else {
        // transpose via LDS: Tt[colv_local][m_local], stride 136 (16B-aligned rows)
        #pragma unroll
        for (int tm = 0; tm < 4; ++tm) {
            const int ml = wrow + tm * 16 + quad * 4;
            #pragma unroll
            for (int tn = 0; tn < 4; ++tn) {
                const int cl = wcol + tn * 16 + l16;
                #pragma unroll
                for (int rg = 0; rg < 4; ++rg)
                    SMEM[cl * 136 + ml + rg] = f2bf(acc[tm][tn][rg]);
            }
        }
        __syncthreads();
        const int row  = tid >> 1;            // colv_local 0..127
        const int half = tid & 1;
        const int colv = (n0 - 512) + row;
        const int vh = colv >> 6, d = colv & 63;
        const int batch = m0 >> 11;
        const int s0 = (m0 & 2047) + half * 64;
        short* dst = vt + ((size_t)((batch * 4 + vh) * 64 + d)) * 2048 + s0;
        const short* src = &SMEM[row * 136 + half * 64];
        #pragma unroll
        for (int i = 0; i < 64; i += 8)
            *(bf16x8*)(dst + i) = *(const bf16x8*)(src + i);
    }
}

// ---------------------------------------------------------------------------
// K2: split-K MFMA flash attention, no-max softmax (bounded scores, linear
// merge). Partials stored in bf16 (halves Op traffic).
__global__ __launch_bounds__(256) void k_attn4(const short* __restrict__ pqk,
                                               const short* __restrict__ vt,
                                               short* __restrict__ Op,
                                               float* __restrict__ Lp){
    const int bx = blockIdx.x;
    const int qt = 31 - (bx / NSPLIT);
    const int s  = bx - (bx / NSPLIT) * NSPLIT;
    const int kv = blockIdx.y, batch = blockIdx.z;
    const int tid = threadIdx.x;
    const int wave = tid >> 6, lane = tid & 63, quad = lane >> 4, l16 = lane & 15;
    const int r = tid >> 2, c = (tid & 3) * 16;
    const int part = (((batch * 4 + kv) * 32 + qt) * NSPLIT + s);

    __shared__ short Ks[64][72];
    __shared__ short Vs[64][72];
    __shared__ short Ps[64][72];

    const size_t qrow = (size_t)(batch * SS + qt * 64 + wave * 16 + l16);
    bf16x8 aq0 = *(const bf16x8*)(pqk + qrow * 512 + kv * 64 + quad * 8);
    bf16x8 aq1 = *(const bf16x8*)(pqk + qrow * 512 + kv * 64 + 32 + quad * 8);

    f32x4 accO[4];
    #pragma unroll
    for (int t = 0; t < 4; ++t) accO[t] = f32x4{0.f, 0.f, 0.f, 0.f};
    float lrow[4] = {0.f, 0.f, 0.f, 0.f};

    bf16x8 rk0, rk1, rv0, rv1;
    int kt = s;
    if (kt <= qt) {
        const short* ksrc = pqk + (size_t)(batch * SS + kt * 64 + r) * 512 + 256 + kv * 64 + c;
        rk0 = *(const bf16x8*)ksrc; rk1 = *(const bf16x8*)(ksrc + 8);
        const short* vsrc = vt + ((size_t)((batch * 4 + kv) * 64 + r)) * 2048 + kt * 64 + c;
        rv0 = *(const bf16x8*)vsrc; rv1 = *(const bf16x8*)(vsrc + 8);
    }
    for (; kt <= qt; kt += NSPLIT) {
        *(bf16x8*)&Ks[r][c]     = rk0;
        *(bf16x8*)&Ks[r][c + 8] = rk1;
        *(bf16x8*)&Vs[r][c]     = rv0;
        *(bf16x8*)&Vs[r][c + 8] = rv1;
        __syncthreads();
        if (kt + NSPLIT <= qt) {
            const short* ksrc = pqk + (size_t)(batch * SS + (kt + NSPLIT) * 64 + r) * 512 + 256 + kv * 64 + c;
            rk0 = *(const bf16x8*)ksrc; rk1 = *(const bf16x8*)(ksrc + 8);
            const short* vsrc = vt + ((size_t)((batch * 4 + kv) * 64 + r)) * 2048 + (kt + NSPLIT) * 64 + c;
            rv0 = *(const bf16x8*)vsrc; rv1 = *(const bf16x8*)(vsrc + 8);
        }

        f32x4 sc[4];
        #pragma unroll
        for (int t = 0; t < 4; ++t) sc[t] = f32x4{0.f, 0.f, 0.f, 0.f};
        #pragma unroll
        for (int ks = 0; ks < 2; ++ks) {
            bf16x8 a = ks ? aq1 : aq0;
            #pragma unroll
            for (int t = 0; t < 4; ++t) {
                bf16x8 b = *(bf16x8*)&Ks[t * 16 + l16][ks * 32 + quad * 8];
                sc[t] = __builtin_amdgcn_mfma_f32_16x16x32_bf16(a, b, sc[t], 0, 0, 0);
            }
        }
        if (kt == qt) {
            #pragma unroll
            for (int t = 0; t < 4; ++t) {
                int colg = t * 16 + l16;
                #pragma unroll
                for (int rg = 0; rg < 4; ++rg)
                    if (colg > wave * 16 + quad * 4 + rg) sc[t][rg] = -1e30f;
            }
        }
        #pragma unroll
        for (int t = 0; t < 4; ++t) {
            #pragma unroll
            for (int rg = 0; rg < 4; ++rg) {
                float p = __expf(sc[t][rg]);
                lrow[rg] += p;
                Ps[wave * 16 + quad * 4 + rg][t * 16 + l16] = f2bf(p);
            }
        }
        #pragma unroll
        for (int ks = 0; ks < 2; ++ks) {
            bf16x8 ap = *(bf16x8*)&Ps[wave * 16 + l16][ks * 32 + quad * 8];
            #pragma unroll
            for (int t = 0; t < 4; ++t) {
                bf16x8 bv = *(bf16x8*)&Vs[t * 16 + l16][ks * 32 + quad * 8];
                accO[t] = __builtin_amdgcn_mfma_f32_16x16x32_bf16(ap, bv, accO[t], 0, 0, 0);
            }
        }
        __syncthreads();
    }
    #pragma unroll
    for (int rg = 0; rg < 4; ++rg) {
        float l = lrow[rg];
        l += __shfl_xor(l, 1);
        l += __shfl_xor(l, 2);
        l += __shfl_xor(l, 4);
        l += __shfl_xor(l, 8);
        lrow[rg] = l;
    }
    #pragma unroll
    for (int rg = 0; rg < 4; ++rg) {
        int row = wave * 16 + quad * 4 + rg;
        #pragma unroll
        for (int t = 0; t < 4; ++t)
            Op[(size_t)part * 4096 + row * 64 + t * 16 + l16] = f2bf(accO[t][rg]);
    }
    if (l16 == 0) {
        #pragma unroll
        for (int rg = 0; rg < 4; ++rg)
            Lp[part * 64 + (wave * 16 + quad * 4 + rg)] = lrow[rg];
    }
}

// K2b: linear merge of NSPLIT bf16 partials -> ao bf16 [4096][256]
__global__ __launch_bounds__(256) void k_combine(const short* __restrict__ Op,
                                                 const float* __restrict__ Lp,
                                                 short* __restrict__ ao){
    const int qt = blockIdx.x, kv = blockIdx.y, batch = blockIdx.z;
    const int tid = threadIdx.x;
    const int rr = tid >> 2, cs = (tid & 3) * 16;
    const int pbase = ((batch * 4 + kv) * 32 + qt) * NSPLIT;
    float lsum = 0.f;
    #pragma unroll
    for (int i = 0; i < NSPLIT; ++i) lsum += Lp[(pbase + i) * 64 + rr];
    float inv = 1.f / lsum;
    float o[16];
    #pragma unroll
    for (int j = 0; j < 16; ++j) o[j] = 0.f;
    #pragma unroll
    for (int i = 0; i < NSPLIT; ++i) {
        const short* src = Op + (size_t)(pbase + i) * 4096 + rr * 64 + cs;
        bf16x8 v0 = *(const bf16x8*)src;
        bf16x8 v1 = *(const bf16x8*)(src + 8);
        #pragma unroll
        for (int j = 0; j < 8; ++j) { o[j] += bf2f(v0[j]); o[j + 8] += bf2f(v1[j]); }
    }
    short* dst = ao + (size_t)(batch * SS + qt * 64 + rr) * 256 + kv * 64 + cs;
    #pragma unroll
    for (int j = 0; j < 16; ++j)
        dst[j] = f2bf(o[j] * inv);
}

// ---------------------------------------------------------------------------
// K3: output projection GEMM, 128x128 tile, register-prefetched. fp32 out.
__global__ __launch_bounds__(256) void k_gemm2(const short* __restrict__ ao,
                                               const short* __restrict__ WoT,
                                               float* __restrict__ out){
    const int m0 = blockIdx.x * 128;
    const int n0 = blockIdx.y * 128;
    const int tid = threadIdx.x;
    const int wave = tid >> 6, lane = tid & 63, quad = lane >> 4, l16 = lane & 15;
    const int wrow = (wave & 1) * 64, wcol = (wave >> 1) * 64;
    const int r = tid >> 2, cc = (tid & 3) * 16;

    __shared__ short As[128][72];
    __shared__ short Bs[128][72];

    f32x4 acc[4][4];
    #pragma unroll
    for (int tm = 0; tm < 4; ++tm)
        #pragma unroll
        for (int tn = 0; tn < 4; ++tn) acc[tm][tn] = f32x4{0.f,0.f,0.f,0.f};

    bf16x8 ra0, ra1, ra2, ra3, rb0, rb1, rb2, rb3;
    {
        const short* a0 = ao + (size_t)(m0 + r) * 256 + cc;
        const short* a1 = a0 + (size_t)64 * 256;
        const short* b0 = WoT + (size_t)(n0 + r) * 256 + cc;
        const short* b1 = b0 + (size_t)64 * 256;
        ra0 = *(const bf16x8*)a0; ra1 = *(const bf16x8*)(a0 + 8);
        ra2 = *(const bf16x8*)a1; ra3 = *(const bf16x8*)(a1 + 8);
        rb0 = *(const bf16x8*)b0; rb1 = *(const bf16x8*)(b0 + 8);
        rb2 = *(const bf16x8*)b1; rb3 = *(const bf16x8*)(b1 + 8);
    }
    for (int k0 = 0; k0 < 256; k0 += 64) {
        *(bf16x8*)&As[r][cc]          = ra0;
        *(bf16x8*)&As[r][cc + 8]      = ra1;
        *(bf16x8*)&As[r + 64][cc]     = ra2;
        *(bf16x8*)&As[r + 64][cc + 8] = ra3;
        *(bf16x8*)&Bs[r][cc]          = rb0;
        *(bf16x8*)&Bs[r][cc + 8]      = rb1;
        *(bf16x8*)&Bs[r + 64][cc]     = rb2;
        *(bf16x8*)&Bs[r + 64][cc + 8] = rb3;
        __syncthreads();
        if (k0 + 64 < 256) {
            const short* a0 = ao + (size_t)(m0 + r) * 256 + k0 + 64 + cc;
            const short* a1 = a0 + (size_t)64 * 256;
            const short* b0 = WoT + (size_t)(n0 + r) * 256 + k0 + 64 + cc;
            const short* b1 = b0 + (size_t)64 * 256;
            ra0 = *(const bf16x8*)a0; ra1 = *(const bf16x8*)(a0 + 8);
            ra2 = *(const bf16x8*)a1; ra3 = *(const bf16x8*)(a1 + 8);
            rb0 = *(const bf16x8*)b0; rb1 = *(const bf16x8*)(b0 + 8);
            rb2 = *(const bf16x8*)b1; rb3 = *(const bf16x8*)(b1 + 8);
        }
        #pragma unroll
        for (int ks = 0; ks < 2; ++ks) {
            bf16x8 a[4];
            #pragma unroll
            for (int tm = 0; tm < 4; ++tm)
                a[tm] = *(bf16x8*)&As[wrow + tm * 16 + l16][ks * 32 + quad * 8];
            #pragma unroll
            for (int tn = 0; tn < 4; ++tn) {
                bf16x8 b = *(bf16x8*)&Bs[wcol + tn * 16 + l16][ks * 32 + quad * 8];
                #pragma unroll
                for (int tm = 0; tm < 4; ++tm)
                    acc[tm][tn] = __builtin_amdgcn_mfma_f32_16x16x32_bf16(a[tm], b, acc[tm][tn], 0, 0, 0);
            }
        }
        __syncthreads();
    }
    #pragma unroll
    for (int tm = 0; tm < 4; ++tm) {
        const int mrow = m0 + wrow + tm * 16 + quad * 4;
        #pragma unroll
        for (int tn = 0; tn < 4; ++tn) {
            const int col = n0 + wcol + tn * 16 + l16;
            #pragma unroll
            for (int rg = 0; rg < 4; ++rg)
                out[(size_t)(mrow + rg) * 1024 + col] = acc[tm][tn][rg];
        }
    }
}

extern "C" void kernel_launch(void* const* d_in, const int* in_sizes, int n_in,
                              void* d_out, int out_size, void* d_ws, size_t ws_size,
                              hipStream_t stream) {
    const float* q_in  = (const float*)d_in[0];
    const float* kv_in = (const float*)d_in[1];
    int wqi = 3;
    for (int i = 2; i < n_in; ++i)
        if (in_sizes[i] == 1024 * 16 * 64) { wqi = i; break; }
    const float* Wq = (const float*)d_in[wqi];
    const float* Wk = (const float*)d_in[wqi + 1];
    const float* Wv = (const float*)d_in[wqi + 2];
    const float* Wo = (const float*)d_in[wqi + 3];
    float* out = (float*)d_out;

    // ws is ~256 MiB (R8-R11 profile). Static disjoint layout, high-water 48 MB:
    char* ws = (char*)d_ws;
    short* WcatT = (short*)(ws);                  // [0, 1.5M)
    short* WoT   = (short*)(ws + 1572864);        // [1.5M, 2M)
    short* ao    = (short*)(ws + 2097152);        // [2M, 4M)
    short* pqk   = (short*)(ws + 4194304);        // [4M, 8M)
    short* vt    = (short*)(ws + 8388608);        // [8M, 10M)
    float* Lp    = (float*)(ws + 10485760);       // [10M, +512K)
    short* Op    = (short*)(ws + 33554432);       // [32M, 48M) bf16 @ NSPLIT=8

    hipLaunchKernelGGL(k_prep_w,  dim3(256),     dim3(256), 0, stream,
                       Wq, Wk, Wv, Wo, WcatT, WoT);
    hipLaunchKernelGGL(k_gemm1,   dim3(32, 6),   dim3(256), 0, stream,
                       q_in, kv_in, WcatT, pqk, vt);
    hipLaunchKernelGGL(k_attn4,   dim3(32 * NSPLIT, 4, 2), dim3(256), 0, stream,
                       pqk, vt, Op, Lp);
    hipLaunchKernelGGL(k_combine, dim3(32, 4, 2), dim3(256), 0, stream,
                       Op, Lp, ao);
    hipLaunchKernelGGL(k_gemm2,   dim3(32, 8),   dim3(256), 0, stream,
                       ao, WoT, out);
}